// Round 6
// baseline (1387.321 us; speedup 1.0000x reference)
//
#include <hip/hip_runtime.h>
#include <hip/hip_bf16.h>
#include <math.h>

#define T_ 6
#define LQ_ 300
#define C_ 256
#define NH_ 8
#define HD_ 32
#define DFF_ 1024
#define LIN_ 16320
#define NQ_ (T_*LQ_)   /* 1800 */
#define GRID_ 512      /* exactly 2 blocks/CU on 256 CUs -> all co-resident */

typedef unsigned int uint32;
typedef unsigned short us;

__device__ __forceinline__ float b2f(us u) {
    union { float f; unsigned i; } x; x.i = ((unsigned)u) << 16; return x.f;
}
__device__ __forceinline__ us f2b(float f) {
    union { float f; unsigned i; } x; x.f = f;
    unsigned r = x.i + 0x7fffu + ((x.i >> 16) & 1u);
    return (us)(r >> 16);
}
__device__ __forceinline__ uint32 pack2(float a, float b) {
    union { __hip_bfloat162 h; uint32 u; } c;
    c.h = __float22bfloat162_rn(make_float2(a, b));
    return c.u;
}

typedef __bf16 bf16x8 __attribute__((ext_vector_type(8)));
typedef float  f32x4  __attribute__((ext_vector_type(4)));

// ---------------------------------------------------------------------------
// grid-wide barrier: device-scope arrival + agent-scope spin. All GRID_ blocks
// are co-resident by construction (launch_bounds + LDS budget), so this cannot
// deadlock. Counter is zeroed by hipMemsetAsync before every launch.
// ---------------------------------------------------------------------------
__device__ __forceinline__ void gridbar(unsigned* bar, unsigned target) {
    __syncthreads();
    if (threadIdx.x == 0) {
        __threadfence();   // release: our phase's writes visible device-wide
        __hip_atomic_fetch_add(bar, 1u, __ATOMIC_RELEASE, __HIP_MEMORY_SCOPE_AGENT);
        while (__hip_atomic_load(bar, __ATOMIC_ACQUIRE, __HIP_MEMORY_SCOPE_AGENT) < target)
            __builtin_amdgcn_s_sleep(8);
        __threadfence();   // acquire: other blocks' writes visible to us
    }
    __syncthreads();
}

// ---------------------------------------------------------------------------
// 64x64-tile GEMM unit (K staged upfront per 256-chunk). A2 optional add.
// ---------------------------------------------------------------------------
__device__ void gemm64_unit(
        us* As, us* Bs, int bm,
        const float* __restrict__ A, const float* __restrict__ A2,
        const float* __restrict__ Bw,
        const float* __restrict__ bias, float* __restrict__ Cmat,
        int ldc, int cn0, int M, int K, bool relu) {
    constexpr int LDA = 40;
    int tid  = threadIdx.x;
    int wave = tid >> 6, lane = tid & 63;
    int wm = (wave >> 1) * 32, wn = (wave & 1) * 32;

    f32x4 acc00 = {0.f,0.f,0.f,0.f}, acc01 = {0.f,0.f,0.f,0.f};
    f32x4 acc10 = {0.f,0.f,0.f,0.f}, acc11 = {0.f,0.f,0.f,0.f};

    int srow = tid >> 2, scol = (tid & 3) * 8;
    int arow = bm + srow;
    const bool aval = arow < M;
    const size_t aoff = (size_t)arow * K + scol;
    const size_t boff = (size_t)srow * K + scol;

    int fr = lane & 15, quad = lane >> 4;
    const us* pa0 = As + (wm + fr) * LDA + quad * 8;
    const us* pa1 = pa0 + 16 * LDA;
    const us* pb0 = Bs + (wn + fr) * LDA + quad * 8;
    const us* pb1 = pb0 + 16 * LDA;

    for (int k0 = 0; k0 < K; k0 += 256) {
        float4 ar[8][2], br[8][2];
        #pragma unroll
        for (int c = 0; c < 8; ++c) {
            int kk = k0 + c * 32;
            if (aval) {
                ar[c][0] = *(const float4*)(A + aoff + kk);
                ar[c][1] = *(const float4*)(A + aoff + kk + 4);
                if (A2) {
                    float4 p0 = *(const float4*)(A2 + aoff + kk);
                    float4 p1 = *(const float4*)(A2 + aoff + kk + 4);
                    ar[c][0].x += p0.x; ar[c][0].y += p0.y; ar[c][0].z += p0.z; ar[c][0].w += p0.w;
                    ar[c][1].x += p1.x; ar[c][1].y += p1.y; ar[c][1].z += p1.z; ar[c][1].w += p1.w;
                }
            } else {
                ar[c][0] = make_float4(0.f,0.f,0.f,0.f);
                ar[c][1] = make_float4(0.f,0.f,0.f,0.f);
            }
            br[c][0] = *(const float4*)(Bw + boff + kk);
            br[c][1] = *(const float4*)(Bw + boff + kk + 4);
        }
        #pragma unroll
        for (int c = 0; c < 8; ++c) {
            uint4 ap, bp;
            ap.x = pack2(ar[c][0].x, ar[c][0].y); ap.y = pack2(ar[c][0].z, ar[c][0].w);
            ap.z = pack2(ar[c][1].x, ar[c][1].y); ap.w = pack2(ar[c][1].z, ar[c][1].w);
            bp.x = pack2(br[c][0].x, br[c][0].y); bp.y = pack2(br[c][0].z, br[c][0].w);
            bp.z = pack2(br[c][1].x, br[c][1].y); bp.w = pack2(br[c][1].z, br[c][1].w);
            __syncthreads();
            *(uint4*)(As + srow * LDA + scol) = ap;
            *(uint4*)(Bs + srow * LDA + scol) = bp;
            __syncthreads();
            bf16x8 a0 = *(const bf16x8*)pa0;
            bf16x8 a1 = *(const bf16x8*)pa1;
            bf16x8 b0 = *(const bf16x8*)pb0;
            bf16x8 b1 = *(const bf16x8*)pb1;
            acc00 = __builtin_amdgcn_mfma_f32_16x16x32_bf16(a0, b0, acc00, 0, 0, 0);
            acc01 = __builtin_amdgcn_mfma_f32_16x16x32_bf16(a0, b1, acc01, 0, 0, 0);
            acc10 = __builtin_amdgcn_mfma_f32_16x16x32_bf16(a1, b0, acc10, 0, 0, 0);
            acc11 = __builtin_amdgcn_mfma_f32_16x16x32_bf16(a1, b1, acc11, 0, 0, 0);
        }
    }

    // C/D layout: n = lane&15, m = quad*4 + reg  [measured m89/m91]
    int n0l = wn + fr, n1l = n0l + 16;
    float bias0 = bias[n0l], bias1 = bias[n1l];
    int mbase = bm + wm + quad * 4;
    #pragma unroll
    for (int r = 0; r < 4; ++r) {
        int m0 = mbase + r, m1 = m0 + 16;
        float v00 = acc00[r] + bias0, v01 = acc01[r] + bias1;
        float v10 = acc10[r] + bias0, v11 = acc11[r] + bias1;
        if (relu) {
            v00 = fmaxf(v00, 0.f); v01 = fmaxf(v01, 0.f);
            v10 = fmaxf(v10, 0.f); v11 = fmaxf(v11, 0.f);
        }
        if (m0 < M) {
            Cmat[(size_t)m0 * ldc + cn0 + n0l] = v00;
            Cmat[(size_t)m0 * ldc + cn0 + n1l] = v01;
        }
        if (m1 < M) {
            Cmat[(size_t)m1 * ldc + cn0 + n0l] = v10;
            Cmat[(size_t)m1 * ldc + cn0 + n1l] = v11;
        }
    }
}

// ---------------------------------------------------------------------------
// Full-width 64x256 tile unit, register-prefetch pipeline.
// MODE 0: bf16 store (value projection).
// MODE 1: epilogue LayerNorm: out_ln = LN(resid + A@W^T + bias)*g + b
//         [+ out2 = out_ln + pos], fp32 stores. (round-4 verified)
// ---------------------------------------------------------------------------
template<int MODE>
__device__ void full_unit(
        char* smem, int bm,
        const float* __restrict__ A, const float* __restrict__ W,
        const float* __restrict__ bias, int M, int K,
        us* __restrict__ out_bf,
        const float* __restrict__ resid, const float* __restrict__ lng,
        const float* __restrict__ lnb, float* __restrict__ out_ln,
        const float* __restrict__ pos, float* __restrict__ out2) {
    constexpr int LDA = 40;
    us* As = (us*)smem;                 // 64*40*2  = 5120 B
    us* Bs = (us*)(smem + 5120);        // 256*40*2 = 20480 B
    float* lred = (float*)(smem + 25600);  // [2][64][4] 2048 B
    float* lmv  = (float*)(smem + 27648);  // [2][64]    512 B
    int tid = threadIdx.x, wave = tid >> 6, lane = tid & 63;
    int fr = lane & 15, quad = lane >> 4;

    f32x4 acc[4][4];
    #pragma unroll
    for (int i = 0; i < 4; ++i)
        #pragma unroll
        for (int j = 0; j < 4; ++j) { f32x4 z = {0.f,0.f,0.f,0.f}; acc[i][j] = z; }

    const int KC = K >> 5;
    float4 av[2], bv[8];
    auto ldA = [&](int c) {
        int k0 = c * 32;
        #pragma unroll
        for (int i = 0; i < 2; ++i) {
            int f = i * 256 + tid;
            int r = bm + (f >> 3);
            if (r < M) av[i] = *(const float4*)(A + (size_t)r * K + k0 + (f & 7) * 4);
            else       av[i] = make_float4(0.f, 0.f, 0.f, 0.f);
        }
    };
    auto ldB = [&](int c) {
        int k0 = c * 32;
        #pragma unroll
        for (int i = 0; i < 8; ++i) {
            int f = i * 256 + tid;
            bv[i] = *(const float4*)(W + (size_t)(f >> 3) * K + k0 + (f & 7) * 4);
        }
    };

    ldA(0); ldB(0);
    for (int c = 0; c < KC; ++c) {
        __syncthreads();
        #pragma unroll
        for (int i = 0; i < 2; ++i) {
            int f = i * 256 + tid;
            uint2 p; p.x = pack2(av[i].x, av[i].y); p.y = pack2(av[i].z, av[i].w);
            *(uint2*)(As + (f >> 3) * LDA + (f & 7) * 4) = p;
        }
        #pragma unroll
        for (int i = 0; i < 8; ++i) {
            int f = i * 256 + tid;
            uint2 p; p.x = pack2(bv[i].x, bv[i].y); p.y = pack2(bv[i].z, bv[i].w);
            *(uint2*)(Bs + (f >> 3) * LDA + (f & 7) * 4) = p;
        }
        __syncthreads();
        if (c + 1 < KC) { ldA(c + 1); ldB(c + 1); }   // prefetch overlaps MFMA
        bf16x8 af[4], bfv[4];
        #pragma unroll
        for (int mt = 0; mt < 4; ++mt)
            af[mt] = *(const bf16x8*)(As + (mt * 16 + fr) * LDA + quad * 8);
        #pragma unroll
        for (int nt = 0; nt < 4; ++nt)
            bfv[nt] = *(const bf16x8*)(Bs + (wave * 64 + nt * 16 + fr) * LDA + quad * 8);
        #pragma unroll
        for (int mt = 0; mt < 4; ++mt)
            #pragma unroll
            for (int nt = 0; nt < 4; ++nt)
                acc[mt][nt] = __builtin_amdgcn_mfma_f32_16x16x32_bf16(af[mt], bfv[nt], acc[mt][nt], 0, 0, 0);
    }

    if (MODE == 0) {
        #pragma unroll
        for (int nt = 0; nt < 4; ++nt) {
            int n = wave * 64 + nt * 16 + fr;
            float bs = bias[n];
            #pragma unroll
            for (int mt = 0; mt < 4; ++mt) {
                int mb2 = bm + mt * 16 + quad * 4;
                #pragma unroll
                for (int r = 0; r < 4; ++r) {
                    int m = mb2 + r;
                    if (m < M) out_bf[(size_t)m * 256 + n] = f2b(acc[mt][nt][r] + bs);
                }
            }
        }
    } else {
        int col[4]; float bcol[4];
        #pragma unroll
        for (int nt = 0; nt < 4; ++nt) {
            col[nt] = wave * 64 + nt * 16 + fr;
            bcol[nt] = bias[col[nt]];
        }
        #pragma unroll
        for (int mt = 0; mt < 4; ++mt) {
            #pragma unroll
            for (int r = 0; r < 4; ++r) {
                int m = bm + mt * 16 + quad * 4 + r;
                #pragma unroll
                for (int nt = 0; nt < 4; ++nt) {
                    float rv = (m < M) ? resid[(size_t)m * 256 + col[nt]] : 0.f;
                    acc[mt][nt][r] += bcol[nt] + rv;
                }
            }
        }
        #pragma unroll
        for (int mt = 0; mt < 4; ++mt) {
            #pragma unroll
            for (int r = 0; r < 4; ++r) {
                float s  = acc[mt][0][r] + acc[mt][1][r] + acc[mt][2][r] + acc[mt][3][r];
                float s2 = acc[mt][0][r]*acc[mt][0][r] + acc[mt][1][r]*acc[mt][1][r]
                         + acc[mt][2][r]*acc[mt][2][r] + acc[mt][3][r]*acc[mt][3][r];
                #pragma unroll
                for (int off = 1; off < 16; off <<= 1) {
                    s  += __shfl_xor(s,  off);
                    s2 += __shfl_xor(s2, off);
                }
                if (fr == 0) {
                    int row = mt * 16 + quad * 4 + r;
                    lred[(0*64 + row)*4 + wave] = s;
                    lred[(1*64 + row)*4 + wave] = s2;
                }
            }
        }
        __syncthreads();
        if (tid < 64) {
            float s  = lred[(0*64+tid)*4+0] + lred[(0*64+tid)*4+1] + lred[(0*64+tid)*4+2] + lred[(0*64+tid)*4+3];
            float s2 = lred[(1*64+tid)*4+0] + lred[(1*64+tid)*4+1] + lred[(1*64+tid)*4+2] + lred[(1*64+tid)*4+3];
            float mean = s * (1.0f / 256.0f);
            float var  = s2 * (1.0f / 256.0f) - mean * mean;
            lmv[0*64+tid] = mean;
            lmv[1*64+tid] = rsqrtf(var + 1e-5f);
        }
        __syncthreads();
        float gcol[4], b2col[4];
        #pragma unroll
        for (int nt = 0; nt < 4; ++nt) { gcol[nt] = lng[col[nt]]; b2col[nt] = lnb[col[nt]]; }
        #pragma unroll
        for (int mt = 0; mt < 4; ++mt) {
            #pragma unroll
            for (int r = 0; r < 4; ++r) {
                int row = mt * 16 + quad * 4 + r;
                int m = bm + row;
                if (m >= M) continue;
                float mean = lmv[0*64+row], rstd = lmv[1*64+row];
                #pragma unroll
                for (int nt = 0; nt < 4; ++nt) {
                    float o = (acc[mt][nt][r] - mean) * rstd * gcol[nt] + b2col[nt];
                    out_ln[(size_t)m * 256 + col[nt]] = o;
                    if (pos) out2[(size_t)m * 256 + col[nt]] = o + pos[(size_t)m * 256 + col[nt]];
                }
            }
        }
    }
}

// ---------------------------------------------------------------------------
// Self-attention unit (body verified in rounds 2-5).
// ---------------------------------------------------------------------------
__device__ void attn_unit(
        char* smem, int t, int h, int q0,
        const float* __restrict__ qk, const float* __restrict__ vb,
        float* __restrict__ sain) {
    uint32* Ksu = (uint32*)smem;               // 300*17*4 = 20400 B
    uint32* Vsu = (uint32*)(smem + 20400);     // 20400 B
    float*  Qs  = (float*)(smem + 40800);      // 4096 B
    float*  ps  = (float*)(smem + 44896);      // 4*304*4 = 4864 B
    int tid = threadIdx.x;

    for (int idx = tid; idx < 300 * 16; idx += 256) {
        int row = idx >> 4, cc = idx & 15;
        float2 kv = *(const float2*)(qk + (size_t)(t * 300 + row) * 512 + 256 + h * 32 + 2 * cc);
        float2 vv = *(const float2*)(vb + (size_t)(t * 300 + row) * 256 + h * 32 + 2 * cc);
        Ksu[row * 17 + cc] = pack2(kv.x, kv.y);
        Vsu[row * 17 + cc] = pack2(vv.x, vv.y);
    }
    for (int idx = tid; idx < 1024; idx += 256) {
        int row = idx >> 5, d = idx & 31;
        int q = q0 + row;
        Qs[idx] = (q < 300) ? qk[(size_t)(t * 300 + q) * 512 + h * 32 + d] : 0.f;
    }
    __syncthreads();

    int wavei = tid >> 6, lane = tid & 63;
    const float scale = 0.17677669529663687f;  // 1/sqrt(32)

    for (int i = 0; i < 8; ++i) {
        int q = q0 + wavei * 8 + i;
        int ql = wavei * 8 + i;
        float qv[32];
        #pragma unroll
        for (int d = 0; d < 32; ++d) qv[d] = Qs[ql * 32 + d];

        float sc[5], mx = -1e30f;
        #pragma unroll
        for (int m = 0; m < 5; ++m) {
            int k = lane + 64 * m;
            float s = -1e30f;
            if (k < 300) {
                s = 0.f;
                #pragma unroll
                for (int dd = 0; dd < 16; ++dd) {
                    uint32 u = Ksu[k * 17 + dd];
                    s += qv[2 * dd]     * b2f((us)u)
                       + qv[2 * dd + 1] * b2f((us)(u >> 16));
                }
                s *= scale;
            }
            sc[m] = s; mx = fmaxf(mx, s);
        }
        #pragma unroll
        for (int off = 1; off < 64; off <<= 1) mx = fmaxf(mx, __shfl_xor(mx, off));
        float sum = 0.f;
        #pragma unroll
        for (int m = 0; m < 5; ++m) {
            int k = lane + 64 * m;
            float ev = (k < 300) ? __expf(sc[m] - mx) : 0.f;
            if (k < 300) ps[wavei * 304 + k] = ev;
            sum += ev;
        }
        #pragma unroll
        for (int off = 1; off < 64; off <<= 1) sum += __shfl_xor(sum, off);
        float inv = 1.f / sum;
        __syncthreads();

        int e16 = lane & 15, kh = lane >> 4;
        float ox = 0.f, oy = 0.f;
        int kbeg = kh * 75;
        for (int k = kbeg; k < kbeg + 75; ++k) {
            float p = ps[wavei * 304 + k];
            uint32 u = Vsu[k * 17 + e16];
            ox += p * b2f((us)u);
            oy += p * b2f((us)(u >> 16));
        }
        ox += __shfl_xor(ox, 16); ox += __shfl_xor(ox, 32);
        oy += __shfl_xor(oy, 16); oy += __shfl_xor(oy, 32);
        if (q < 300 && kh == 0) {
            *(float2*)(sain + (size_t)(t * 300 + q) * 256 + h * 32 + 2 * e16)
                = make_float2(ox * inv, oy * inv);
        }
        __syncthreads();
    }
}

// ---------------------------------------------------------------------------
// aw softmax + deformable bilinear sampling unit (body verified).
// ---------------------------------------------------------------------------
__device__ void sample_unit(
        int b,
        const float* __restrict__ awl,   const float* __restrict__ refp,
        const float* __restrict__ cfo,   const float* __restrict__ ofo,
        const float* __restrict__ soffo, const float* __restrict__ toffo,
        const us* __restrict__ value, float* __restrict__ samp) {
    const int HL[4] = {96, 48, 24, 12};
    const int WL[4] = {128, 64, 32, 16};
    const int ST[4] = {0, 12288, 15360, 16128};
    int t = b / LQ_;
    int tid = threadIdx.x, h = tid >> 5, d = tid & 31;
    size_t row = (size_t)b;

    float logit = awl[row * 256 + h * 32 + d];
    float mx = logit;
    #pragma unroll
    for (int off = 16; off >= 1; off >>= 1) mx = fmaxf(mx, __shfl_xor(mx, off, 32));
    float e = __expf(logit - mx);
    float s = e;
    #pragma unroll
    for (int off = 16; off >= 1; off >>= 1) s += __shfl_xor(s, off, 32);
    float myw = e / s;

    float acc = 0.f;
    for (int smp = 0; smp < 32; ++smp) {
        int l = smp >> 3, j = smp & 7;
        float wgt = __shfl(myw, smp, 32);
        int Hl = HL[l], Wl = WL[l], st = ST[l];
        float rx = refp[(row * 4 + l) * 2 + 0];
        float ry = refp[(row * 4 + l) * 2 + 1];
        float lx, ly; int frame;
        if (j < 4) {
            lx = rx + cfo[(row * 4 + l) * 2 + 0]
               + soffo[row * 256 + h * 32 + l * 8 + j * 2 + 0] / (float)Wl;
            ly = ry + cfo[(row * 4 + l) * 2 + 1]
               + soffo[row * 256 + h * 32 + l * 8 + j * 2 + 1] / (float)Hl;
            frame = t;
        } else {
            int wi = (j - 4) >> 1, p = (j - 4) & 1;
            lx = rx + ofo[((row * 2 + wi) * 4 + l) * 2 + 0]
               + toffo[row * 256 + h * 32 + l * 8 + wi * 4 + p * 2 + 0] / (float)Wl;
            ly = ry + ofo[((row * 2 + wi) * 4 + l) * 2 + 1]
               + toffo[row * 256 + h * 32 + l * 8 + wi * 4 + p * 2 + 1] / (float)Hl;
            frame = t + (wi == 0 ? -1 : 1);
            frame = frame < 0 ? 0 : (frame > T_ - 1 ? T_ - 1 : frame);
        }
        float x = lx * (float)Wl - 0.5f, y = ly * (float)Hl - 0.5f;
        float xf = floorf(x), yf = floorf(y);
        float wx = x - xf, wy = y - yf;
        int x0 = (int)xf, y0 = (int)yf;
        float sacc = 0.f;
        size_t base = ((size_t)frame * LIN_ + st) * 256 + h * 32 + d;
        #pragma unroll
        for (int cy = 0; cy < 2; ++cy) {
            int yi = y0 + cy;
            if (yi < 0 || yi >= Hl) continue;
            float wyv = cy ? wy : 1.f - wy;
            #pragma unroll
            for (int cx = 0; cx < 2; ++cx) {
                int xi = x0 + cx;
                if (xi < 0 || xi >= Wl) continue;
                float wv = wyv * (cx ? wx : 1.f - wx);
                sacc += wv * b2f(value[base + (size_t)(yi * Wl + xi) * 256]);
            }
        }
        acc += wgt * sacc;
    }
    samp[row * 256 + h * 32 + d] = acc;
}

// ---------------------------------------------------------------------------
struct MArgs {
    const float *tgt, *qpos, *refp, *cfo, *ofo, *src;
    const float *in_w, *in_b, *sa_w, *sa_b;
    const float *n1g, *n1b, *n2g, *n2b, *n3g, *n3b;
    const float *val_w, *val_b, *soff_w, *soff_b, *toff_w, *toff_b, *attnw, *attnb;
    const float *cross_w, *cross_b, *lin1_w, *lin1_b, *lin2_w, *lin2_b;
    us* value;
    float *qkb, *vbuf, *ff1, *sain, *soffo, *tgt2, *qc, *toffo, *tgt3;
    float* out;
    unsigned* bar;
};

__global__ __launch_bounds__(256, 2) void mega(MArgs a) {
    __shared__ __align__(16) char smem[49760];
    us* As64 = (us*)smem;
    us* Bs64 = (us*)(smem + 5120);
    const float* awl = a.sain;   // aliased (sain dead after saout)

    // ---- P1: value projection (units 0..1529) + qkv projection (1530..1877)
    for (int u = blockIdx.x; u < 1878; u += GRID_) {
        __syncthreads();
        if (u < 1530) {
            full_unit<0>(smem, u * 64, a.src, a.val_w, a.val_b, T_ * LIN_, 256,
                         a.value, nullptr, nullptr, nullptr, nullptr, nullptr, nullptr);
        } else {
            int u2 = u - 1530, y = u2 / 29, bm = (u2 % 29) * 64;
            if (y < 8)
                gemm64_unit(As64, Bs64, bm, a.tgt, a.qpos, a.in_w + (size_t)y * 64 * 256,
                            a.in_b + y * 64, a.qkb, 512, y * 64, NQ_, 256, false);
            else
                gemm64_unit(As64, Bs64, bm, a.tgt, nullptr,
                            a.in_w + (size_t)(512 + (y - 8) * 64) * 256,
                            a.in_b + 512 + (y - 8) * 64, a.vbuf, 256, (y - 8) * 64,
                            NQ_, 256, false);
        }
    }
    gridbar(a.bar, 1 * GRID_);

    // ---- P2: self-attention (480 units)
    for (int u = blockIdx.x; u < 480; u += GRID_) {
        __syncthreads();
        int x = u % 48, q0 = (u / 48) * 32;
        attn_unit(smem, x / 8, x % 8, q0, a.qkb, a.vbuf, a.sain);
    }
    gridbar(a.bar, 2 * GRID_);

    // ---- P3: sa-out GEMM + residual + LN2 -> tgt2, qc = tgt2 + qpos (29 units)
    for (int u = blockIdx.x; u < 29; u += GRID_) {
        __syncthreads();
        full_unit<1>(smem, u * 64, a.sain, a.sa_w, a.sa_b, NQ_, 256, nullptr,
                     a.tgt, a.n2g, a.n2b, a.tgt2, a.qpos, a.qc);
    }
    gridbar(a.bar, 3 * GRID_);

    // ---- P4: soff/toff/attn-weight projections (348 units). awl aliases sain.
    for (int u = blockIdx.x; u < 348; u += GRID_) {
        __syncthreads();
        int y = u / 29, bm = (u % 29) * 64, g = y >> 2, cn0 = (y & 3) * 64;
        const float* W; const float* bias; float* O;
        if (g == 0)      { W = a.soff_w; bias = a.soff_b; O = a.soffo; }
        else if (g == 1) { W = a.toff_w; bias = a.toff_b; O = a.toffo; }
        else             { W = a.attnw;  bias = a.attnb;  O = (float*)awl; }
        gemm64_unit(As64, Bs64, bm, a.qc, nullptr, W + (size_t)cn0 * 256, bias + cn0,
                    O, 256, cn0, NQ_, 256, false);
    }
    gridbar(a.bar, 4 * GRID_);

    // ---- P5: deformable sampling (1800 units). samp aliases qc (qc dead).
    for (int u = blockIdx.x; u < 1800; u += GRID_)
        sample_unit(u, awl, a.refp, a.cfo, a.ofo, a.soffo, a.toffo, a.value, a.qc);
    gridbar(a.bar, 5 * GRID_);

    // ---- P6: cross GEMM + residual + LN1 -> tgt3 (29 units)
    for (int u = blockIdx.x; u < 29; u += GRID_) {
        __syncthreads();
        full_unit<1>(smem, u * 64, a.qc, a.cross_w, a.cross_b, NQ_, 256, nullptr,
                     a.tgt2, a.n1g, a.n1b, a.tgt3, nullptr, nullptr);
    }
    gridbar(a.bar, 6 * GRID_);

    // ---- P7: ffn1 relu (464 units)
    for (int u = blockIdx.x; u < 464; u += GRID_) {
        __syncthreads();
        int bm = (u / 16) * 64, cn0 = (u % 16) * 64;
        gemm64_unit(As64, Bs64, bm, a.tgt3, nullptr, a.lin1_w + (size_t)cn0 * 256,
                    a.lin1_b + cn0, a.ff1, 1024, cn0, NQ_, 256, true);
    }
    gridbar(a.bar, 7 * GRID_);

    // ---- P8: ffn2 + residual + LN3 -> out (29 units, K=1024)
    for (int u = blockIdx.x; u < 29; u += GRID_) {
        __syncthreads();
        full_unit<1>(smem, u * 64, a.ff1, a.lin2_w, a.lin2_b, NQ_, 1024, nullptr,
                     a.tgt3, a.n3g, a.n3b, a.out, nullptr, nullptr);
    }
}

// ---------------------------------------------------------------------------
extern "C" void kernel_launch(void* const* d_in, const int* in_sizes, int n_in,
                              void* d_out, int out_size, void* d_ws, size_t ws_size,
                              hipStream_t stream) {
    (void)in_sizes; (void)n_in; (void)out_size; (void)ws_size;
    typedef const float* cfp;
    MArgs a;
    a.tgt   = (cfp)d_in[0];
    a.qpos  = (cfp)d_in[1];
    a.refp  = (cfp)d_in[2];
    a.cfo   = (cfp)d_in[3];
    a.ofo   = (cfp)d_in[4];
    a.src   = (cfp)d_in[5];
    a.in_w  = (cfp)d_in[9];
    a.in_b  = (cfp)d_in[10];
    a.sa_w  = (cfp)d_in[11];
    a.sa_b  = (cfp)d_in[12];
    a.n1g = (cfp)d_in[13]; a.n1b = (cfp)d_in[14];
    a.n2g = (cfp)d_in[15]; a.n2b = (cfp)d_in[16];
    a.n3g = (cfp)d_in[17]; a.n3b = (cfp)d_in[18];
    a.val_w = (cfp)d_in[19]; a.val_b = (cfp)d_in[20];
    a.soff_w = (cfp)d_in[21]; a.soff_b = (cfp)d_in[22];
    a.toff_w = (cfp)d_in[23]; a.toff_b = (cfp)d_in[24];
    a.attnw = (cfp)d_in[25]; a.attnb = (cfp)d_in[26];
    a.cross_w = (cfp)d_in[27]; a.cross_b = (cfp)d_in[28];
    a.lin1_w = (cfp)d_in[29]; a.lin1_b = (cfp)d_in[30];
    a.lin2_w = (cfp)d_in[31]; a.lin2_b = (cfp)d_in[32];

    // ---- workspace arena
    char* wp = (char*)d_ws;
    const size_t ROWB = (size_t)NQ_ * 256 * 4;
    a.value = (us*)wp;  wp += (size_t)T_ * LIN_ * 256 * 2;     // bf16, 25 MB
    float* bigreg = (float*)wp;  wp += 4 * ROWB;               // qkb|vbuf, then ff1
    a.qkb  = bigreg;
    a.vbuf = bigreg + (size_t)NQ_ * 512;
    a.ff1  = bigreg;
    a.sain  = (float*)wp; wp += ROWB;   // awl aliases after attn consumed
    a.soffo = (float*)wp; wp += ROWB;
    a.tgt2  = (float*)wp; wp += ROWB;
    a.qc    = (float*)wp; wp += ROWB;   // samp aliases after proj3
    a.toffo = (float*)wp; wp += ROWB;
    a.tgt3  = (float*)wp; wp += ROWB;
    a.bar   = (unsigned*)wp; wp += 256;
    a.out   = (float*)d_out;

    hipMemsetAsync(a.bar, 0, 256, stream);
    mega<<<dim3(GRID_), dim3(256), 0, stream>>>(a);
}

// Round 7
// 374.141 us; speedup vs baseline: 3.7080x; 3.7080x over previous
//
#include <hip/hip_runtime.h>
#include <hip/hip_bf16.h>
#include <math.h>

#define T_ 6
#define LQ_ 300
#define C_ 256
#define NH_ 8
#define HD_ 32
#define DFF_ 1024
#define LIN_ 16320
#define NQ_ (T_*LQ_)   /* 1800 */

typedef unsigned int uint32;
typedef unsigned short us;

__device__ __forceinline__ float b2f(us u) {
    union { float f; unsigned i; } x; x.i = ((unsigned)u) << 16; return x.f;
}
__device__ __forceinline__ us f2b(float f) {
    union { float f; unsigned i; } x; x.f = f;
    unsigned r = x.i + 0x7fffu + ((x.i >> 16) & 1u);
    return (us)(r >> 16);
}
__device__ __forceinline__ uint32 pack2(float a, float b) {
    union { __hip_bfloat162 h; uint32 u; } c;
    c.h = __float22bfloat162_rn(make_float2(a, b));
    return c.u;
}

typedef __bf16 bf16x8 __attribute__((ext_vector_type(8)));
typedef float  f32x4  __attribute__((ext_vector_type(4)));

// ---------------------------------------------------------------------------
// 64x64-tile GEMM unit (K staged upfront per 256-chunk; A2 optional add).
// Verified rounds 3-5.
// ---------------------------------------------------------------------------
__device__ __forceinline__ void gemm64_core(
        us* As, us* Bs, int bm,
        const float* __restrict__ A, const float* __restrict__ A2,
        const float* __restrict__ Bw,
        const float* __restrict__ bias, float* __restrict__ Cmat,
        int ldc, int cn0, int M, int K, bool relu) {
    constexpr int LDA = 40;
    int tid  = threadIdx.x;
    int wave = tid >> 6, lane = tid & 63;
    int wm = (wave >> 1) * 32, wn = (wave & 1) * 32;

    f32x4 acc00 = {0.f,0.f,0.f,0.f}, acc01 = {0.f,0.f,0.f,0.f};
    f32x4 acc10 = {0.f,0.f,0.f,0.f}, acc11 = {0.f,0.f,0.f,0.f};

    int srow = tid >> 2, scol = (tid & 3) * 8;
    int arow = bm + srow;
    const bool aval = arow < M;
    const size_t aoff = (size_t)arow * K + scol;
    const size_t boff = (size_t)srow * K + scol;

    int fr = lane & 15, quad = lane >> 4;
    const us* pa0 = As + (wm + fr) * LDA + quad * 8;
    const us* pa1 = pa0 + 16 * LDA;
    const us* pb0 = Bs + (wn + fr) * LDA + quad * 8;
    const us* pb1 = pb0 + 16 * LDA;

    for (int k0 = 0; k0 < K; k0 += 256) {
        float4 ar[8][2], br[8][2];
        #pragma unroll
        for (int c = 0; c < 8; ++c) {
            int kk = k0 + c * 32;
            if (aval) {
                ar[c][0] = *(const float4*)(A + aoff + kk);
                ar[c][1] = *(const float4*)(A + aoff + kk + 4);
                if (A2) {
                    float4 p0 = *(const float4*)(A2 + aoff + kk);
                    float4 p1 = *(const float4*)(A2 + aoff + kk + 4);
                    ar[c][0].x += p0.x; ar[c][0].y += p0.y; ar[c][0].z += p0.z; ar[c][0].w += p0.w;
                    ar[c][1].x += p1.x; ar[c][1].y += p1.y; ar[c][1].z += p1.z; ar[c][1].w += p1.w;
                }
            } else {
                ar[c][0] = make_float4(0.f,0.f,0.f,0.f);
                ar[c][1] = make_float4(0.f,0.f,0.f,0.f);
            }
            br[c][0] = *(const float4*)(Bw + boff + kk);
            br[c][1] = *(const float4*)(Bw + boff + kk + 4);
        }
        #pragma unroll
        for (int c = 0; c < 8; ++c) {
            uint4 ap, bp;
            ap.x = pack2(ar[c][0].x, ar[c][0].y); ap.y = pack2(ar[c][0].z, ar[c][0].w);
            ap.z = pack2(ar[c][1].x, ar[c][1].y); ap.w = pack2(ar[c][1].z, ar[c][1].w);
            bp.x = pack2(br[c][0].x, br[c][0].y); bp.y = pack2(br[c][0].z, br[c][0].w);
            bp.z = pack2(br[c][1].x, br[c][1].y); bp.w = pack2(br[c][1].z, br[c][1].w);
            __syncthreads();
            *(uint4*)(As + srow * LDA + scol) = ap;
            *(uint4*)(Bs + srow * LDA + scol) = bp;
            __syncthreads();
            bf16x8 a0 = *(const bf16x8*)pa0;
            bf16x8 a1 = *(const bf16x8*)pa1;
            bf16x8 b0 = *(const bf16x8*)pb0;
            bf16x8 b1 = *(const bf16x8*)pb1;
            acc00 = __builtin_amdgcn_mfma_f32_16x16x32_bf16(a0, b0, acc00, 0, 0, 0);
            acc01 = __builtin_amdgcn_mfma_f32_16x16x32_bf16(a0, b1, acc01, 0, 0, 0);
            acc10 = __builtin_amdgcn_mfma_f32_16x16x32_bf16(a1, b0, acc10, 0, 0, 0);
            acc11 = __builtin_amdgcn_mfma_f32_16x16x32_bf16(a1, b1, acc11, 0, 0, 0);
        }
    }

    // C/D layout: n = lane&15, m = quad*4 + reg  [measured m89/m91]
    int n0l = wn + fr, n1l = n0l + 16;
    float bias0 = bias[n0l], bias1 = bias[n1l];
    int mbase = bm + wm + quad * 4;
    #pragma unroll
    for (int r = 0; r < 4; ++r) {
        int m0 = mbase + r, m1 = m0 + 16;
        float v00 = acc00[r] + bias0, v01 = acc01[r] + bias1;
        float v10 = acc10[r] + bias0, v11 = acc11[r] + bias1;
        if (relu) {
            v00 = fmaxf(v00, 0.f); v01 = fmaxf(v01, 0.f);
            v10 = fmaxf(v10, 0.f); v11 = fmaxf(v11, 0.f);
        }
        if (m0 < M) {
            Cmat[(size_t)m0 * ldc + cn0 + n0l] = v00;
            Cmat[(size_t)m0 * ldc + cn0 + n1l] = v01;
        }
        if (m1 < M) {
            Cmat[(size_t)m1 * ldc + cn0 + n0l] = v10;
            Cmat[(size_t)m1 * ldc + cn0 + n1l] = v11;
        }
    }
}

template<bool RELU>
__global__ __launch_bounds__(256, 2) void gemm_std(
        const float* __restrict__ A, const float* __restrict__ W,
        const float* __restrict__ bias, float* __restrict__ C,
        int M, int N, int K) {
    __shared__ __align__(16) us As[64 * 40];
    __shared__ __align__(16) us Bs[64 * 40];
    int cn0 = blockIdx.y * 64;
    gemm64_core(As, Bs, blockIdx.x * 64, A, nullptr, W + (size_t)cn0 * K, bias + cn0,
                C, N, cn0, M, K, RELU);
}

// fused soff/toff/attn-weight projections from qc. grid.y = 12.
__global__ __launch_bounds__(256, 2) void gemm_proj3(
        const float* __restrict__ qc,
        const float* __restrict__ sw, const float* __restrict__ sb,
        const float* __restrict__ tw, const float* __restrict__ tb,
        const float* __restrict__ aw, const float* __restrict__ ab,
        float* __restrict__ so, float* __restrict__ to, float* __restrict__ ao) {
    __shared__ __align__(16) us As[64 * 40];
    __shared__ __align__(16) us Bs[64 * 40];
    int y = blockIdx.y, g = y >> 2, cn0 = (y & 3) * 64;
    const float* W; const float* bias; float* O;
    if (g == 0)      { W = sw; bias = sb; O = so; }
    else if (g == 1) { W = tw; bias = tb; O = to; }
    else             { W = aw; bias = ab; O = ao; }
    gemm64_core(As, Bs, blockIdx.x * 64, qc, nullptr, W + (size_t)cn0 * 256, bias + cn0,
                O, 256, cn0, NQ_, 256, false);
}

// ---------------------------------------------------------------------------
// Fused dispatch #1: blocks [0,1530) = value projection (64x256 full-width,
// register-prefetch pipeline, LDS-staged coalesced bf16 epilogue);
// blocks [1530,1878) = qkv projection tiles (q = tgt+qpos fused).
// ---------------------------------------------------------------------------
__global__ __launch_bounds__(256, 2) void vqkv_kernel(
        const float* __restrict__ src, const float* __restrict__ val_w,
        const float* __restrict__ val_b, us* __restrict__ value,
        const float* __restrict__ tgt, const float* __restrict__ qpos,
        const float* __restrict__ in_w, const float* __restrict__ in_b,
        float* __restrict__ qkb, float* __restrict__ vbuf) {
    __shared__ __align__(16) char smem[32768];
    if (blockIdx.x >= 1530) {
        // ---- qkv tile
        us* As64 = (us*)smem;
        us* Bs64 = (us*)(smem + 5120);
        int u = blockIdx.x - 1530, y = u / 29, bm = (u % 29) * 64;
        if (y < 8)
            gemm64_core(As64, Bs64, bm, tgt, qpos, in_w + (size_t)y * 64 * 256,
                        in_b + y * 64, qkb, 512, y * 64, NQ_, 256, false);
        else
            gemm64_core(As64, Bs64, bm, tgt, nullptr,
                        in_w + (size_t)(512 + (y - 8) * 64) * 256,
                        in_b + 512 + (y - 8) * 64, vbuf, 256, (y - 8) * 64,
                        NQ_, 256, false);
        return;
    }
    // ---- value tile: 64 rows x 256 cols
    constexpr int LDA = 40;
    us* As = (us*)smem;                 // 5120 B
    us* Bs = (us*)(smem + 5120);        // 20480 B
    int tid = threadIdx.x, wave = tid >> 6, lane = tid & 63;
    int bm = blockIdx.x * 64;
    int fr = lane & 15, quad = lane >> 4;

    f32x4 acc[4][4];
    #pragma unroll
    for (int i = 0; i < 4; ++i)
        #pragma unroll
        for (int j = 0; j < 4; ++j) { f32x4 z = {0.f,0.f,0.f,0.f}; acc[i][j] = z; }

    float4 av[2], bv[8];
    auto ldA = [&](int c) {
        int k0 = c * 32;
        #pragma unroll
        for (int i = 0; i < 2; ++i) {
            int f = i * 256 + tid;
            av[i] = *(const float4*)(src + (size_t)(bm + (f >> 3)) * 256 + k0 + (f & 7) * 4);
        }
    };
    auto ldB = [&](int c) {
        int k0 = c * 32;
        #pragma unroll
        for (int i = 0; i < 8; ++i) {
            int f = i * 256 + tid;
            bv[i] = *(const float4*)(val_w + (size_t)(f >> 3) * 256 + k0 + (f & 7) * 4);
        }
    };

    ldA(0); ldB(0);
    for (int c = 0; c < 8; ++c) {
        if (c) __syncthreads();
        #pragma unroll
        for (int i = 0; i < 2; ++i) {
            int f = i * 256 + tid;
            uint2 p; p.x = pack2(av[i].x, av[i].y); p.y = pack2(av[i].z, av[i].w);
            *(uint2*)(As + (f >> 3) * LDA + (f & 7) * 4) = p;
        }
        #pragma unroll
        for (int i = 0; i < 8; ++i) {
            int f = i * 256 + tid;
            uint2 p; p.x = pack2(bv[i].x, bv[i].y); p.y = pack2(bv[i].z, bv[i].w);
            *(uint2*)(Bs + (f >> 3) * LDA + (f & 7) * 4) = p;
        }
        __syncthreads();
        if (c + 1 < 8) { ldA(c + 1); ldB(c + 1); }   // prefetch overlaps MFMA
        bf16x8 af[4], bfv[4];
        #pragma unroll
        for (int mt = 0; mt < 4; ++mt)
            af[mt] = *(const bf16x8*)(As + (mt * 16 + fr) * LDA + quad * 8);
        #pragma unroll
        for (int nt = 0; nt < 4; ++nt)
            bfv[nt] = *(const bf16x8*)(Bs + (wave * 64 + nt * 16 + fr) * LDA + quad * 8);
        #pragma unroll
        for (int mt = 0; mt < 4; ++mt)
            #pragma unroll
            for (int nt = 0; nt < 4; ++nt)
                acc[mt][nt] = __builtin_amdgcn_mfma_f32_16x16x32_bf16(af[mt], bfv[nt], acc[mt][nt], 0, 0, 0);
    }

    // Epilogue: stage bf16 C tile in LDS (overlaying As/Bs), then coalesced
    // dwordx4 global stores (16 B/lane) — replaces 16 scattered 2-B stores.
    __syncthreads();
    us* Cs = (us*)smem;   // 64 x 256 us = 32768 B
    #pragma unroll
    for (int nt = 0; nt < 4; ++nt) {
        int n = wave * 64 + nt * 16 + fr;
        float bs = val_b[n];
        #pragma unroll
        for (int mt = 0; mt < 4; ++mt) {
            int rowb = mt * 16 + quad * 4;
            #pragma unroll
            for (int r = 0; r < 4; ++r)
                Cs[(rowb + r) * 256 + n] = f2b(acc[mt][nt][r] + bs);
        }
    }
    __syncthreads();
    #pragma unroll
    for (int p = 0; p < 4; ++p) {
        int flat = p * 256 + tid;
        int row = flat >> 5, c16 = (flat & 31) * 8;
        uint4 v = *(const uint4*)(Cs + row * 256 + c16);
        *(uint4*)(value + (size_t)(bm + row) * 256 + c16) = v;
    }
}

// ---------------------------------------------------------------------------
// Self-attention (unchanged — verified rounds 2-6)
// ---------------------------------------------------------------------------
__global__ __launch_bounds__(256) void attn_kernel(
        const float* __restrict__ qk, const float* __restrict__ vb,
        float* __restrict__ sain) {
    __shared__ uint32 Ksu[300 * 17];
    __shared__ uint32 Vsu[300 * 17];
    __shared__ float  Qs[32 * 32];
    __shared__ float  ps[4][304];
    int t = blockIdx.x / NH_, h = blockIdx.x % NH_;
    int q0 = blockIdx.y * 32;
    int tid = threadIdx.x;

    for (int idx = tid; idx < 300 * 16; idx += 256) {
        int row = idx >> 4, cc = idx & 15;
        float2 kv = *(const float2*)(qk + (size_t)(t * 300 + row) * 512 + 256 + h * 32 + 2 * cc);
        float2 vv = *(const float2*)(vb + (size_t)(t * 300 + row) * 256 + h * 32 + 2 * cc);
        Ksu[row * 17 + cc] = pack2(kv.x, kv.y);
        Vsu[row * 17 + cc] = pack2(vv.x, vv.y);
    }
    for (int idx = tid; idx < 1024; idx += 256) {
        int row = idx >> 5, d = idx & 31;
        int q = q0 + row;
        Qs[idx] = (q < 300) ? qk[(size_t)(t * 300 + q) * 512 + h * 32 + d] : 0.f;
    }
    __syncthreads();

    int wavei = tid >> 6, lane = tid & 63;
    const float scale = 0.17677669529663687f;  // 1/sqrt(32)

    for (int i = 0; i < 8; ++i) {
        int q = q0 + wavei * 8 + i;
        int ql = wavei * 8 + i;
        float qv[32];
        #pragma unroll
        for (int d = 0; d < 32; ++d) qv[d] = Qs[ql * 32 + d];

        float sc[5], mx = -1e30f;
        #pragma unroll
        for (int m = 0; m < 5; ++m) {
            int k = lane + 64 * m;
            float s = -1e30f;
            if (k < 300) {
                s = 0.f;
                #pragma unroll
                for (int dd = 0; dd < 16; ++dd) {
                    uint32 u = Ksu[k * 17 + dd];
                    s += qv[2 * dd]     * b2f((us)u)
                       + qv[2 * dd + 1] * b2f((us)(u >> 16));
                }
                s *= scale;
            }
            sc[m] = s; mx = fmaxf(mx, s);
        }
        #pragma unroll
        for (int off = 1; off < 64; off <<= 1) mx = fmaxf(mx, __shfl_xor(mx, off));
        float sum = 0.f;
        #pragma unroll
        for (int m = 0; m < 5; ++m) {
            int k = lane + 64 * m;
            float ev = (k < 300) ? __expf(sc[m] - mx) : 0.f;
            if (k < 300) ps[wavei][k] = ev;
            sum += ev;
        }
        #pragma unroll
        for (int off = 1; off < 64; off <<= 1) sum += __shfl_xor(sum, off);
        float inv = 1.f / sum;
        __syncthreads();

        int e16 = lane & 15, kh = lane >> 4;
        float ox = 0.f, oy = 0.f;
        int kbeg = kh * 75;
        for (int k = kbeg; k < kbeg + 75; ++k) {
            float p = ps[wavei][k];
            uint32 u = Vsu[k * 17 + e16];
            ox += p * b2f((us)u);
            oy += p * b2f((us)(u >> 16));
        }
        ox += __shfl_xor(ox, 16); ox += __shfl_xor(ox, 32);
        oy += __shfl_xor(oy, 16); oy += __shfl_xor(oy, 32);
        if (q < 300 && kh == 0) {
            *(float2*)(sain + (size_t)(t * 300 + q) * 256 + h * 32 + 2 * e16)
                = make_float2(ox * inv, oy * inv);
        }
        __syncthreads();
    }
}

// ---------------------------------------------------------------------------
// aw softmax + deformable bilinear sampling, v2: branchless OOB (zero-weight +
// clamped index), per-(t,q) scalars sourced via width-32 shuffles instead of
// redundant per-sample scalar loads -> flat gather stream the scheduler can
// keep ~dozens of loads in flight on.
// ---------------------------------------------------------------------------
__global__ __launch_bounds__(256) void sample_kernel(
        const float* __restrict__ awl,   const float* __restrict__ refp,
        const float* __restrict__ cfo,   const float* __restrict__ ofo,
        const float* __restrict__ soffo, const float* __restrict__ toffo,
        const us* __restrict__ value, float* __restrict__ samp) {
    int b = blockIdx.x;
    int t = b / LQ_;
    int tid = threadIdx.x, h = tid >> 5, d = tid & 31;
    size_t row = (size_t)b;

    // softmax over this head's 32 logits
    float logit = awl[row * 256 + (size_t)tid];
    float mx = logit;
    #pragma unroll
    for (int off = 16; off >= 1; off >>= 1) mx = fmaxf(mx, __shfl_xor(mx, off, 32));
    float e = __expf(logit - mx);
    float s = e;
    #pragma unroll
    for (int off = 16; off >= 1; off >>= 1) s += __shfl_xor(s, off, 32);
    float myw = e / s;

    // per-thread slices for shuffle-broadcast
    float soff_my = soffo[row * 256 + (size_t)tid];
    float toff_my = toffo[row * 256 + (size_t)tid];
    float rp_my = (d < 8)  ? refp[row * 8 + d]  : 0.f;
    float cf_my = (d < 8)  ? cfo[row * 8 + d]   : 0.f;
    float of_my = (d < 16) ? ofo[row * 16 + d]  : 0.f;

    float acc = 0.f;
    #pragma unroll
    for (int smp = 0; smp < 32; ++smp) {
        const int l = smp >> 3, j = smp & 7;
        // compile-time level constants
        const int Hl = (l == 0) ? 96 : (l == 1) ? 48 : (l == 2) ? 24 : 12;
        const int Wl = (l == 0) ? 128 : (l == 1) ? 64 : (l == 2) ? 32 : 16;
        const int st = (l == 0) ? 0 : (l == 1) ? 12288 : (l == 2) ? 15360 : 16128;
        const float iW = 1.f / (float)Wl, iH = 1.f / (float)Hl;

        float wgt = __shfl(myw, smp, 32);
        float rx = __shfl(rp_my, l * 2 + 0, 32);
        float ry = __shfl(rp_my, l * 2 + 1, 32);
        float lx, ly; int frame;
        if (j < 4) {
            lx = rx + __shfl(cf_my, l * 2 + 0, 32) + __shfl(soff_my, l * 8 + j * 2 + 0, 32) * iW;
            ly = ry + __shfl(cf_my, l * 2 + 1, 32) + __shfl(soff_my, l * 8 + j * 2 + 1, 32) * iH;
            frame = t;
        } else {
            const int wi = (j - 4) >> 1, p = (j - 4) & 1;
            lx = rx + __shfl(of_my, wi * 8 + l * 2 + 0, 32) + __shfl(toff_my, l * 8 + wi * 4 + p * 2 + 0, 32) * iW;
            ly = ry + __shfl(of_my, wi * 8 + l * 2 + 1, 32) + __shfl(toff_my, l * 8 + wi * 4 + p * 2 + 1, 32) * iH;
            frame = t + (wi == 0 ? -1 : 1);
            frame = frame < 0 ? 0 : (frame > T_ - 1 ? T_ - 1 : frame);
        }
        float x = lx * (float)Wl - 0.5f, y = ly * (float)Hl - 0.5f;
        float xf = floorf(x), yf = floorf(y);
        float wx = x - xf, wy = y - yf;
        int x0 = (int)xf, y0 = (int)yf;
        int x1 = x0 + 1, y1 = y0 + 1;
        // validity -> multiplicative masks; clamp indices
        float vx0 = (x0 >= 0 && x0 < Wl) ? 1.f : 0.f;
        float vx1 = (x1 >= 0 && x1 < Wl) ? 1.f : 0.f;
        float vy0 = (y0 >= 0 && y0 < Hl) ? 1.f : 0.f;
        float vy1 = (y1 >= 0 && y1 < Hl) ? 1.f : 0.f;
        int cx0 = min(max(x0, 0), Wl - 1), cx1 = min(max(x1, 0), Wl - 1);
        int cy0 = min(max(y0, 0), Hl - 1), cy1 = min(max(y1, 0), Hl - 1);
        size_t base = ((size_t)frame * LIN_ + st) * 256 + h * 32 + d;
        float g00 = b2f(value[base + (size_t)(cy0 * Wl + cx0) * 256]);
        float g01 = b2f(value[base + (size_t)(cy0 * Wl + cx1) * 256]);
        float g10 = b2f(value[base + (size_t)(cy1 * Wl + cx0) * 256]);
        float g11 = b2f(value[base + (size_t)(cy1 * Wl + cx1) * 256]);
        float w00 = (1.f - wx) * (1.f - wy) * vx0 * vy0;
        float w01 = wx * (1.f - wy) * vx1 * vy0;
        float w10 = (1.f - wx) * wy * vx0 * vy1;
        float w11 = wx * wy * vx1 * vy1;
        acc += wgt * (g00 * w00 + g01 * w01 + g10 * w10 + g11 * w11);
    }
    samp[row * 256 + (size_t)tid] = acc;
}

// ---------------------------------------------------------------------------
// out = LN(x + y)*g + b ; optional out2 = out + pos. One block per row.
// ---------------------------------------------------------------------------
__global__ __launch_bounds__(256) void ln_kernel(
        const float* __restrict__ x, const float* __restrict__ y,
        const float* __restrict__ g, const float* __restrict__ bb,
        float* __restrict__ out,
        const float* __restrict__ pos, float* __restrict__ out2) {
    int row = blockIdx.x, c = threadIdx.x;
    size_t idx = (size_t)row * 256 + c;
    float v = x[idx] + y[idx];
    float s = v;
    #pragma unroll
    for (int off = 1; off < 64; off <<= 1) s += __shfl_xor(s, off);
    __shared__ float red[4];
    int wv = c >> 6;
    if ((c & 63) == 0) red[wv] = s;
    __syncthreads();
    float mean = (red[0] + red[1] + red[2] + red[3]) * (1.0f / 256.0f);
    float dv = v - mean;
    float s2 = dv * dv;
    #pragma unroll
    for (int off = 1; off < 64; off <<= 1) s2 += __shfl_xor(s2, off);
    __syncthreads();
    if ((c & 63) == 0) red[wv] = s2;
    __syncthreads();
    float var = (red[0] + red[1] + red[2] + red[3]) * (1.0f / 256.0f);
    float o = dv * rsqrtf(var + 1e-5f) * g[c] + bb[c];
    out[idx] = o;
    if (out2) out2[idx] = o + pos[idx];
}

// ---------------------------------------------------------------------------
extern "C" void kernel_launch(void* const* d_in, const int* in_sizes, int n_in,
                              void* d_out, int out_size, void* d_ws, size_t ws_size,
                              hipStream_t stream) {
    (void)in_sizes; (void)n_in; (void)out_size; (void)ws_size;
    typedef const float* cfp;
    cfp tgt   = (cfp)d_in[0];
    cfp qpos  = (cfp)d_in[1];
    cfp refp  = (cfp)d_in[2];
    cfp cfo   = (cfp)d_in[3];
    cfp ofo   = (cfp)d_in[4];
    cfp src   = (cfp)d_in[5];
    cfp in_proj_w = (cfp)d_in[9];
    cfp in_proj_b = (cfp)d_in[10];
    cfp sa_out_w  = (cfp)d_in[11];
    cfp sa_out_b  = (cfp)d_in[12];
    cfp n1g = (cfp)d_in[13], n1b = (cfp)d_in[14];
    cfp n2g = (cfp)d_in[15], n2b = (cfp)d_in[16];
    cfp n3g = (cfp)d_in[17], n3b = (cfp)d_in[18];
    cfp value_w = (cfp)d_in[19], value_b = (cfp)d_in[20];
    cfp soff_w = (cfp)d_in[21], soff_b = (cfp)d_in[22];
    cfp toff_w = (cfp)d_in[23], toff_b = (cfp)d_in[24];
    cfp attn_w = (cfp)d_in[25], attn_b = (cfp)d_in[26];
    cfp cross_w = (cfp)d_in[27], cross_b = (cfp)d_in[28];
    cfp lin1_w = (cfp)d_in[29], lin1_b = (cfp)d_in[30];
    cfp lin2_w = (cfp)d_in[31], lin2_b = (cfp)d_in[32];

    // ---- workspace arena (lifetime-aliased; launches are stream-ordered)
    char* wp = (char*)d_ws;
    const size_t ROWB = (size_t)NQ_ * 256 * 4;
    us* value = (us*)wp;  wp += (size_t)T_ * LIN_ * 256 * 2;   // bf16, 25 MB
    float* bigreg = (float*)wp;  wp += 4 * ROWB;               // qkb|vbuf, then ff1
    float* qkb  = bigreg;                                      // NQ x 512
    float* vbuf = bigreg + (size_t)NQ_ * 512;                  // NQ x 256
    float* ff1  = bigreg;                                      // NQ x 1024
    float* sain   = (float*)wp; wp += ROWB;   float* awl    = sain;
    float* sap    = (float*)wp; wp += ROWB;   float* soffo  = sap;
    float* tgt2   = (float*)wp; wp += ROWB;   float* ff2    = tgt2;
    float* qc     = (float*)wp; wp += ROWB;   float* samp   = qc;
    float* toffo  = (float*)wp; wp += ROWB;
    float* crossp = (float*)wp; wp += ROWB;
    float* tgt3   = (float*)wp; wp += ROWB;

    dim3 blk(256);
    const int mb = (NQ_ + 63) / 64;  // 29

    // D1: value projection (1530 blocks) + qkv projection (348 blocks) fused
    vqkv_kernel<<<dim3(1530 + 348), blk, 0, stream>>>(
        src, value_w, value_b, value, tgt, qpos, in_proj_w, in_proj_b, qkb, vbuf);
    // D2: self attention
    attn_kernel<<<dim3(T_ * NH_, 10), blk, 0, stream>>>(qkb, vbuf, sain);
    // D3: sa-out projection
    gemm_std<false><<<dim3(mb, 4), blk, 0, stream>>>(sain, sa_out_w, sa_out_b, sap, NQ_, 256, 256);
    // D4: tgt2 = LN(tgt + sa); qc = tgt2 + qpos
    ln_kernel<<<dim3(NQ_), blk, 0, stream>>>(tgt, sap, n2g, n2b, tgt2, qpos, qc);
    // D5: soff/toff/attn-weight projections
    gemm_proj3<<<dim3(mb, 12), blk, 0, stream>>>(qc, soff_w, soff_b, toff_w, toff_b,
                                                 attn_w, attn_b, soffo, toffo, awl);
    // D6: fused aw-softmax + deformable sampling
    sample_kernel<<<dim3(NQ_), blk, 0, stream>>>(awl, refp, cfo, ofo, soffo, toffo, value, samp);
    // D7: cross projection
    gemm_std<false><<<dim3(mb, 4), blk, 0, stream>>>(samp, cross_w, cross_b, crossp, NQ_, 256, 256);
    // D8: tgt3 = LN(tgt2 + cross)
    ln_kernel<<<dim3(NQ_), blk, 0, stream>>>(tgt2, crossp, n1g, n1b, tgt3, nullptr, nullptr);
    // D9: ffn1 (relu)
    gemm_std<true><<<dim3(mb, 16), blk, 0, stream>>>(tgt3, lin1_w, lin1_b, ff1, NQ_, 1024, 256);
    // D10: ffn2
    gemm_std<false><<<dim3(mb, 4), blk, 0, stream>>>(ff1, lin2_w, lin2_b, ff2, NQ_, 256, 1024);
    // D11: out = LN(tgt3 + ff)
    ln_kernel<<<dim3(NQ_), blk, 0, stream>>>(tgt3, ff2, n3g, n3b, (float*)d_out, nullptr, nullptr);
}